// Round 6
// baseline (1904.661 us; speedup 1.0000x reference)
//
#include <hip/hip_runtime.h>
#include <hip/hip_cooperative_groups.h>
#include <stdint.h>

namespace cg = cooperative_groups;

// ---------------------------------------------------------------------------
// aggregated_embedding: heap binary-tree aggregation, 11 levels.
// out = root + (elu(elu(x@WinT+b_in)@W1T+b1)@W2T+b2), x=[root,left,right]
// Round 6: ONE cooperative kernel (convert + all 11 levels, grid.sync between
// levels). Cross-round accounting showed ~25us per graph dispatch (~300us for
// 12 launches) dominating the total — per-kernel tweaks R2-R5 never touched it.
// Per level: grid-stride 32-row tiles, 3-buffer LDS rotation:
//   root in S[r] (kept for residual), left S[l], right S[m];
//   children gathered async at kstep4 of root pass; root(t+stride) gathered
//   into S[m] during GEMM2 (m's reads done); rotation r,l,m <- m,r,l.
// All gathers via global_load_lds (0 VGPRs); XOR-swizzled LDS rows.
// ws layout:
//   [0)            Ebf   32064*256 bf16
//   [16,416,768)   Winbf 256*768  bf16   (row-major [n][k] = MFMA B-frag order)
//   [16,809,984)   W1bf  256*256  bf16
//   [16,941,056)   W2bf  256*256  bf16
//   [17,072,128)   curA  64*1024*256 bf16
//   [50,626,560)   curB  64*512*256 bf16
// ---------------------------------------------------------------------------

typedef __attribute__((ext_vector_type(8))) short short8;   // 8 x bf16 frag
typedef __attribute__((ext_vector_type(4))) float f32x4;    // MFMA C/D

typedef const __attribute__((address_space(1))) unsigned int* gas_ptr;
typedef __attribute__((address_space(3))) unsigned int* las_ptr;

#define TOK_N 4095
#define RR 32                       // rows per tile (MT=2)

__device__ __forceinline__ unsigned short f32_to_bf16(float f) {
    union { float f; unsigned u; } v; v.f = f;
    return (unsigned short)((v.u + 0x7fffu + ((v.u >> 16) & 1u)) >> 16);  // RNE
}
__device__ __forceinline__ float bf16_to_f32(unsigned short u) {
    union { unsigned u; float f; } v; v.u = ((unsigned)u) << 16; return v.f;
}

// ---------------------------------------------------------------------------
// One K=256 MFMA pass (MT=2). A-frags from swizzled LDS; B-frags from L2.
// B schedule: ksteps 0,1,6,7 preloaded upfront; 2..5 rolling 2-deep (last
// mid-pass B-load at kstep 3). late() at kstep 4 — after every B-load of this
// pass, so B-frag vmcnt waits never drain late()'s async gathers.
// ---------------------------------------------------------------------------
template<int WROW, typename F>
__device__ __forceinline__ void run_pass(const unsigned short* __restrict__ Xs,
                                         const unsigned short* __restrict__ wlane,
                                         int kbase, f32x4 (&acc)[2][4],
                                         int l15, int q, F&& late)
{
    const int xm = l15 & 7;
    short8 bb[2][4], bt[2][4];
#pragma unroll
    for (int d = 0; d < 2; ++d)
#pragma unroll
        for (int nt = 0; nt < 4; ++nt)
            bb[d][nt] = *(const short8*)(wlane + (size_t)(nt * 16) * WROW + kbase + d * 32);
#pragma unroll
    for (int d = 0; d < 2; ++d)
#pragma unroll
        for (int nt = 0; nt < 4; ++nt)
            bt[d][nt] = *(const short8*)(wlane + (size_t)(nt * 16) * WROW + kbase + (6 + d) * 32);
#pragma unroll
    for (int k = 0; k < 8; ++k) {
        if (k == 4) {
            __builtin_amdgcn_sched_barrier(0);
            late();
            __builtin_amdgcn_sched_barrier(0);
        }
        short8 a[2];
        const int sl = (((4 * k + q) ^ xm) << 3);       // swizzled chunk * 8
#pragma unroll
        for (int mt = 0; mt < 2; ++mt)
            a[mt] = *(const short8*)(Xs + (mt * 16 + l15) * 256 + sl);
#pragma unroll
        for (int mt = 0; mt < 2; ++mt)
#pragma unroll
            for (int nt = 0; nt < 4; ++nt)
                acc[mt][nt] = __builtin_amdgcn_mfma_f32_16x16x32_bf16(
                    a[mt], (k >= 6) ? bt[k - 6][nt] : bb[k & 1][nt],
                    acc[mt][nt], 0, 0, 0);
        if (k < 4) {
#pragma unroll
            for (int nt = 0; nt < 4; ++nt)
                bb[k & 1][nt] = *(const short8*)(wlane + (size_t)(nt * 16) * WROW + kbase + (k + 2) * 32);
        }
    }
}

__global__ __launch_bounds__(256, 3)
void tree_all(const int* __restrict__ tokens,
              const float* __restrict__ Ef,
              const float* __restrict__ Winf,
              const float* __restrict__ b_in,
              const float* __restrict__ W1f,
              const float* __restrict__ b1,
              const float* __restrict__ W2f,
              const float* __restrict__ b2,
              unsigned short* __restrict__ Ebf,
              unsigned short* __restrict__ Win,
              unsigned short* __restrict__ W1,
              unsigned short* __restrict__ W2,
              unsigned short* __restrict__ curA,
              unsigned short* __restrict__ curB,
              float* __restrict__ out)
{
    __shared__ unsigned short S[3][RR * 256];   // 49152 B -> 3 blocks/CU
    cg::grid_group grid = cg::this_grid();

    // ---- phase 0: fp32 -> bf16 convert (grid-stride) --------------------
    {
        const int nE = 32064 * 256, nWin = 256 * 768, nW = 256 * 256;
        const int total4 = (nE + nWin + 2 * nW) >> 2;
        for (int i = blockIdx.x * blockDim.x + threadIdx.x; i < total4;
             i += gridDim.x * blockDim.x) {
            int idx = i << 2;
            const float* src; unsigned short* dst; int off;
            if (idx < nE)                  { src = Ef;  dst = Ebf; off = idx; }
            else if (idx < nE + nWin)      { src = Winf; dst = Win; off = idx - nE; }
            else if (idx < nE + nWin + nW) { src = W1f; dst = W1;  off = idx - nE - nWin; }
            else                           { src = W2f; dst = W2;  off = idx - nE - nWin - nW; }
            float4 f = *(const float4*)(src + off);
            ushort4 o;
            o.x = f32_to_bf16(f.x); o.y = f32_to_bf16(f.y);
            o.z = f32_to_bf16(f.z); o.w = f32_to_bf16(f.w);
            *(ushort4*)(dst + off) = o;
        }
    }
    __threadfence();
    grid.sync();

    const int tid  = threadIdx.x;
    const int lane = tid & 63;
    const int wid  = tid >> 6;
    const int l15  = lane & 15;
    const int q    = lane >> 4;
    const int n0   = wid * 64;

    // biases preloaded once
    float bva[4], bvb[4], bvc[4];
#pragma unroll
    for (int nt = 0; nt < 4; ++nt) {
        bva[nt] = b_in[n0 + nt * 16 + l15];
        bvb[nt] = b1[n0 + nt * 16 + l15];
        bvc[nt] = b2[n0 + nt * 16 + l15];
    }
    const unsigned short* winlane = Win + q * 8 + (size_t)(n0 + l15) * 768;
    const unsigned short* w1lane  = W1  + q * 8 + (size_t)(n0 + l15) * 256;
    const unsigned short* w2lane  = W2  + q * 8 + (size_t)(n0 + l15) * 256;

    f32x4 acc[2][4];
    auto init_acc = [&](const float* bv) {
#pragma unroll
        for (int mt = 0; mt < 2; ++mt)
#pragma unroll
            for (int nt = 0; nt < 4; ++nt)
                acc[mt][nt] = (f32x4){bv[nt], bv[nt], bv[nt], bv[nt]};
    };
    auto store_elu = [&](unsigned short* dst) {
#pragma unroll
        for (int mt = 0; mt < 2; ++mt)
#pragma unroll
            for (int nt = 0; nt < 4; ++nt)
#pragma unroll
                for (int rr = 0; rr < 4; ++rr) {
                    int row = mt * 16 + q * 4 + rr;
                    int col = n0 + nt * 16 + l15;
                    float h = acc[mt][nt][rr];
                    h = h > 0.f ? h : (__expf(h) - 1.f);
                    int slot = (col >> 3) ^ (row & 7);
                    dst[row * 256 + slot * 8 + (col & 7)] = f32_to_bf16(h);
                }
    };

    int r = 0, l = 1, m = 2;                       // buffer rotation state
    const unsigned short* cin = curB;              // unused at first level
    unsigned short* cout = curA;

    for (int L = 1024; L >= 1; L >>= 1) {
        const int logL  = 31 - __builtin_clz((unsigned)L);
        const int tiles = 2 * L;
        const int first = (L == 1024);
        const int last  = (L == 1);

        // async gather of one 256-wide phase of tile `tile` into dst
        auto gather = [&](int p, int tile, unsigned short* dst) {
#pragma unroll
            for (int it = 0; it < RR / 8; ++it) {
                const int base_r = wid * (RR / 4) + it * 2;
                const int rw = base_r + (lane >> 5);
                const unsigned short* src;
                {
                    int g = tile * RR + rw;
                    int b = g >> logL;
                    int i = g - (b << logL);
                    if (p == 0) {
                        int tok = tokens[b * TOK_N + (L - 1) + i];
                        src = Ebf + (size_t)tok * 256;
                    } else if (first) {
                        int tok = tokens[b * TOK_N + 2047 + 2 * i + (p - 1)];
                        src = Ebf + (size_t)tok * 256;
                    } else {
                        src = cin + ((size_t)b * (2 * L) + 2 * i + (p - 1)) * 256;
                    }
                }
                const int c = (lane & 31) ^ (rw & 7);
                __builtin_amdgcn_global_load_lds(
                    (gas_ptr)(const void*)(src + c * 8),
                    (las_ptr)(void*)(dst + base_r * 256), 16, 0, 0);
            }
        };

        int t = blockIdx.x;
        if (t < tiles) gather(0, t, S[r]);         // serial first root
        for (; t < tiles; t += gridDim.x) {
            __syncthreads();                       // root landed in S[r]

            // GEMM1: root pass; children gathered async at kstep 4
            init_acc(bva);
            run_pass<768>(S[r], winlane, 0, acc, l15, q, [&]() {
                gather(1, t, S[l]);
                gather(2, t, S[m]);
            });
            __syncthreads();                       // drains children gathers
            run_pass<768>(S[l], winlane, 256, acc, l15, q, []() {});
            __syncthreads();
            run_pass<768>(S[m], winlane, 512, acc, l15, q, []() {});
            store_elu(S[l]);                       // l-reads done pre-pass2
            __syncthreads();

            // GEMM2; root(t+stride) prefetched into S[m] (m reads done)
            init_acc(bvb);
            const bool pre = (t + (int)gridDim.x) < tiles;
            run_pass<256>(S[l], w1lane, 0, acc, l15, q, [&]() {
                if (pre) gather(0, t + gridDim.x, S[m]);
            });
            __syncthreads();                       // drains root prefetch
            store_elu(S[l]);                       // in place
            __syncthreads();

            // GEMM3
            init_acc(bvc);
            run_pass<256>(S[l], w2lane, 0, acc, l15, q, []() {});

            // epilogue 3: o = root(S[r]) + H3 (+b2 in acc), no elu
            if (last) {
#pragma unroll
                for (int mt = 0; mt < 2; ++mt)
#pragma unroll
                    for (int nt = 0; nt < 4; ++nt)
#pragma unroll
                        for (int rr = 0; rr < 4; ++rr) {
                            int row = mt * 16 + q * 4 + rr;
                            int col = n0 + nt * 16 + l15;
                            int slot = (col >> 3) ^ (row & 7);
                            float o = acc[mt][nt][rr] +
                                      bf16_to_f32(S[r][row * 256 + slot * 8 + (col & 7)]);
                            out[(size_t)(t * RR + row) * 256 + col] = o;
                        }
            } else {
#pragma unroll
                for (int mt = 0; mt < 2; ++mt)
#pragma unroll
                    for (int nt = 0; nt < 4; ++nt)
#pragma unroll
                        for (int rr = 0; rr < 4; ++rr) {
                            int row = mt * 16 + q * 4 + rr;
                            int col = n0 + nt * 16 + l15;
                            int slot = (col >> 3) ^ (row & 7);
                            int a = row * 256 + slot * 8 + (col & 7);
                            float o = acc[mt][nt][rr] + bf16_to_f32(S[r][a]);
                            S[r][a] = f32_to_bf16(o);     // lane-private in-place
                        }
                __syncthreads();
                // coalesced bf16 store (de-swizzled 16B chunks)
                const int s   = tid & 31;
                const int sub = tid >> 5;
#pragma unroll
                for (int it = 0; it < RR / 8; ++it) {
                    int rw = it * 8 + sub;
                    int c = s ^ (rw & 7);
                    *(short8*)(cout + (size_t)(t * RR + rw) * 256 + c * 8) =
                        *(const short8*)(S[r] + rw * 256 + s * 8);
                }
            }
            // rotate buffers: next root is in old m
            int nr = m; m = l; l = r; r = nr;
        }
        __threadfence();
        grid.sync();                               // level boundary
        cin = cout;
        cout = (cout == curA) ? curB : curA;
    }
}

extern "C" void kernel_launch(void* const* d_in, const int* in_sizes, int n_in,
                              void* d_out, int out_size, void* d_ws, size_t ws_size,
                              hipStream_t stream) {
    const int*   tokens = (const int*)  d_in[0];
    const float* E      = (const float*)d_in[1];
    const float* W_in   = (const float*)d_in[2];
    const float* b_in   = (const float*)d_in[3];
    const float* W1     = (const float*)d_in[4];
    const float* b1     = (const float*)d_in[5];
    const float* W2     = (const float*)d_in[6];
    const float* b2     = (const float*)d_in[7];
    float* out = (float*)d_out;
    char* ws = (char*)d_ws;

    unsigned short* Ebf   = (unsigned short*)(ws);
    unsigned short* Winbf = (unsigned short*)(ws + 16416768);
    unsigned short* W1bf  = (unsigned short*)(ws + 16809984);
    unsigned short* W2bf  = (unsigned short*)(ws + 16941056);
    unsigned short* curA  = (unsigned short*)(ws + 17072128);
    unsigned short* curB  = (unsigned short*)(ws + 50626560);

    int maxB = 0;
    hipOccupancyMaxActiveBlocksPerMultiprocessor(&maxB, (const void*)tree_all, 256, 0);
    if (maxB < 1) maxB = 1;
    if (maxB > 3) maxB = 3;
    int grid = 256 * maxB;

    void* args[] = { (void*)&tokens, (void*)&E, (void*)&W_in, (void*)&b_in,
                     (void*)&W1, (void*)&b1, (void*)&W2, (void*)&b2,
                     (void*)&Ebf, (void*)&Winbf, (void*)&W1bf, (void*)&W2bf,
                     (void*)&curA, (void*)&curB, (void*)&out };
    hipLaunchCooperativeKernel((const void*)tree_all, dim3(grid), dim3(256),
                               args, 0, stream);
}

// Round 7
// 745.380 us; speedup vs baseline: 2.5553x; 2.5553x over previous
//
#include <hip/hip_runtime.h>
#include <stdint.h>

// ---------------------------------------------------------------------------
// aggregated_embedding: heap binary-tree aggregation, 11 levels.
// out = root + (elu(elu(x@WinT+b_in)@W1T+b1)@W2T+b2), x=[root,left,right]
// Round 7: register-resident B pipeline. Key fact (R2-R6 post-mortems):
// __syncthreads drains vmcnt, but PREFETCHED DATA SURVIVES IN REGISTERS.
// Each K=256 pass consumes B-frags prefetched during the previous pass via a
// circular 4-group buffer: k<4 loads (cur,k+4); k>=4 loads (next,k-4).
// Barriers only ever wait on loads >=3 ksteps old -> near-free drains.
// Structure per 32-row tile (3 LDS buffers S0=root,S1=left,S2=right):
//   gather(root)+preload B | pass1(S0; children gathered at k4) | bar |
//   pass2(S1) pass3(S2) [no bar between] | bar | ep1->S1 | bar |
//   pass4(S1) | bar | ep2->S1 | bar | pass5(S1) | ep3(+root from S0) | bar |
//   coalesced bf16 store.
// Levels 1024..64 as per-level kernels (one tile/block); L=32..1 in ONE
// subtree-per-batch kernel (64 blocks) using the same pipeline, children for
// L<=16 staged LDS->LDS from a P buffer. 7 dispatches total.
// ws layout:
//   [0)            Ebf   32064*256 bf16
//   [16,416,768)   Winbf 256*768  bf16   (row-major [n][k] = MFMA B-frag order)
//   [16,809,984)   W1bf  256*256  bf16
//   [16,941,056)   W2bf  256*256  bf16
//   [17,072,128)   curA  64*1024*256 bf16
//   [50,626,560)   curB  64*512*256 bf16
// ---------------------------------------------------------------------------

typedef __attribute__((ext_vector_type(8))) short short8;   // 8 x bf16 frag
typedef __attribute__((ext_vector_type(4))) float f32x4;    // MFMA C/D

typedef const __attribute__((address_space(1))) unsigned int* gas_ptr;
typedef __attribute__((address_space(3))) unsigned int* las_ptr;

#define TOK_N 4095
#define RR 32

__device__ __forceinline__ unsigned short f32_to_bf16(float f) {
    union { float f; unsigned u; } v; v.f = f;
    return (unsigned short)((v.u + 0x7fffu + ((v.u >> 16) & 1u)) >> 16);  // RNE
}
__device__ __forceinline__ float bf16_to_f32(unsigned short u) {
    union { unsigned u; float f; } v; v.u = ((unsigned)u) << 16; return v.f;
}

__global__ void convert_f32_bf16(const float* __restrict__ E,
                                 const float* __restrict__ Win,
                                 const float* __restrict__ W1,
                                 const float* __restrict__ W2,
                                 unsigned short* __restrict__ Ebf,
                                 unsigned short* __restrict__ Winbf,
                                 unsigned short* __restrict__ W1bf,
                                 unsigned short* __restrict__ W2bf) {
    const int nE = 32064 * 256, nWin = 256 * 768, nW = 256 * 256;
    const int total4 = (nE + nWin + 2 * nW) >> 2;
    for (int i = blockIdx.x * blockDim.x + threadIdx.x; i < total4;
         i += gridDim.x * blockDim.x) {
        int idx = i << 2;
        const float* src; unsigned short* dst; int off;
        if (idx < nE)                  { src = E;   dst = Ebf;   off = idx; }
        else if (idx < nE + nWin)      { src = Win; dst = Winbf; off = idx - nE; }
        else if (idx < nE + nWin + nW) { src = W1;  dst = W1bf;  off = idx - nE - nWin; }
        else                           { src = W2;  dst = W2bf;  off = idx - nE - nWin - nW; }
        float4 f = *(const float4*)(src + off);
        ushort4 o;
        o.x = f32_to_bf16(f.x); o.y = f32_to_bf16(f.y);
        o.z = f32_to_bf16(f.z); o.w = f32_to_bf16(f.w);
        *(ushort4*)(dst + off) = o;
    }
}

// ---------------------------------------------------------------------------
// run_pass: one K=256 pass, MT=2 (32 rows x 64 cols/wave). bb is a circular
// 4-group register pipeline: on ENTRY bb[j] = B(cur, curK + j*32) (prefetched
// by the previous pass or manually). k<4 reloads (cur, k+4); k>=4 reloads
// (next, k-4) so the NEXT pass starts with its B in registers. late() at k==4
// (after all cur-pass B issues; next-B loads issued after it keep gathers
// covered by later waits). NT = nt stride in elements (16*WROW).
// ---------------------------------------------------------------------------
template<typename F>
__device__ __forceinline__ void run_pass(const unsigned short* __restrict__ Xs,
                                         const unsigned short* __restrict__ curW,
                                         int curNT, int curK,
                                         const unsigned short* __restrict__ nxtW,
                                         int nxtNT, int nxtK, bool hasNext,
                                         short8 (&bb)[4][4], f32x4 (&acc)[2][4],
                                         int l15, int q, F&& late)
{
    const int xm = l15 & 7;
#pragma unroll
    for (int k = 0; k < 8; ++k) {
        if (k == 4) {
            __builtin_amdgcn_sched_barrier(0);
            late();
            __builtin_amdgcn_sched_barrier(0);
        }
        short8 a0, a1;
        const int sl = (((4 * k + q) ^ xm) << 3);
        a0 = *(const short8*)(Xs + l15 * 256 + sl);
        a1 = *(const short8*)(Xs + (16 + l15) * 256 + sl);
        short8 bc[4];
#pragma unroll
        for (int nt = 0; nt < 4; ++nt) bc[nt] = bb[k & 3][nt];
#pragma unroll
        for (int nt = 0; nt < 4; ++nt)
            acc[0][nt] = __builtin_amdgcn_mfma_f32_16x16x32_bf16(a0, bc[nt], acc[0][nt], 0, 0, 0);
#pragma unroll
        for (int nt = 0; nt < 4; ++nt)
            acc[1][nt] = __builtin_amdgcn_mfma_f32_16x16x32_bf16(a1, bc[nt], acc[1][nt], 0, 0, 0);
        if (k < 4) {
#pragma unroll
            for (int nt = 0; nt < 4; ++nt)
                bb[k & 3][nt] = *(const short8*)(curW + nt * curNT + curK + (k + 4) * 32);
        } else if (hasNext) {
#pragma unroll
            for (int nt = 0; nt < 4; ++nt)
                bb[k & 3][nt] = *(const short8*)(nxtW + nt * nxtNT + nxtK + (k - 4) * 32);
        }
    }
}

// ---------------------------------------------------------------------------
// tree_level: one 32-row tile per block; levels 1024..64.
// ---------------------------------------------------------------------------
__global__ __launch_bounds__(256, 3)
void tree_level(const int* __restrict__ tokens,
                const unsigned short* __restrict__ Ebf,
                const unsigned short* __restrict__ Win,
                const unsigned short* __restrict__ W1,
                const unsigned short* __restrict__ W2,
                const float* __restrict__ b_in,
                const float* __restrict__ b1,
                const float* __restrict__ b2,
                const unsigned short* __restrict__ cur_in,
                unsigned short* __restrict__ cur_out,
                int L, int logL, int first)
{
    __shared__ unsigned short S0[RR * 256];
    __shared__ unsigned short S1[RR * 256];
    __shared__ unsigned short S2[RR * 256];

    const int tid  = threadIdx.x;
    const int lane = tid & 63;
    const int wid  = tid >> 6;
    const int l15  = lane & 15;
    const int q    = lane >> 4;
    const int n0   = wid * 64;
    const int blk  = blockIdx.x;
    const int s    = tid & 31;
    const int sub  = tid >> 5;

    auto gather = [&](int p, unsigned short* dst) {
#pragma unroll
        for (int it = 0; it < 4; ++it) {
            const int base_r = wid * 8 + it * 2;
            const int r = base_r + (lane >> 5);
            const unsigned short* src;
            {
                int g = blk * RR + r;
                int b = g >> logL;
                int i = g - (b << logL);
                if (p == 0) {
                    int tok = tokens[b * TOK_N + (L - 1) + i];
                    src = Ebf + (size_t)tok * 256;
                } else if (first) {
                    int tok = tokens[b * TOK_N + 2047 + 2 * i + (p - 1)];
                    src = Ebf + (size_t)tok * 256;
                } else {
                    src = cur_in + ((size_t)b * (2 * L) + 2 * i + (p - 1)) * 256;
                }
            }
            const int c = (lane & 31) ^ (r & 7);
            __builtin_amdgcn_global_load_lds(
                (gas_ptr)(const void*)(src + c * 8),
                (las_ptr)(void*)(dst + base_r * 256), 16, 0, 0);
        }
    };

    float bva[4], bvb[4], bvc[4];
#pragma unroll
    for (int nt = 0; nt < 4; ++nt) {
        bva[nt] = b_in[n0 + nt * 16 + l15];
        bvb[nt] = b1[n0 + nt * 16 + l15];
        bvc[nt] = b2[n0 + nt * 16 + l15];
    }
    const unsigned short* winlane = Win + q * 8 + (size_t)(n0 + l15) * 768;
    const unsigned short* w1lane  = W1  + q * 8 + (size_t)(n0 + l15) * 256;
    const unsigned short* w2lane  = W2  + q * 8 + (size_t)(n0 + l15) * 256;

    f32x4 acc[2][4];
    auto init_acc = [&](const float* bv) {
#pragma unroll
        for (int mt = 0; mt < 2; ++mt)
#pragma unroll
            for (int nt = 0; nt < 4; ++nt)
                acc[mt][nt] = (f32x4){bv[nt], bv[nt], bv[nt], bv[nt]};
    };
    auto store_elu = [&](unsigned short* dst) {
#pragma unroll
        for (int mt = 0; mt < 2; ++mt)
#pragma unroll
            for (int nt = 0; nt < 4; ++nt)
#pragma unroll
                for (int rr = 0; rr < 4; ++rr) {
                    int row = mt * 16 + q * 4 + rr;
                    int col = n0 + nt * 16 + l15;
                    float h = acc[mt][nt][rr];
                    h = h > 0.f ? h : (__expf(h) - 1.f);
                    int slot = (col >> 3) ^ (row & 7);
                    dst[row * 256 + slot * 8 + (col & 7)] = f32_to_bf16(h);
                }
    };

    short8 bb[4][4];
    auto noop = []() {};

    // prologue: root gather + first B preload (order: gathers first)
    gather(0, S0);
#pragma unroll
    for (int j = 0; j < 4; ++j)
#pragma unroll
        for (int nt = 0; nt < 4; ++nt)
            bb[j][nt] = *(const short8*)(winlane + nt * 12288 + j * 32);
    __syncthreads();

    init_acc(bva);
    run_pass(S0, winlane, 12288, 0, winlane, 12288, 256, true, bb, acc, l15, q,
             [&]() { gather(1, S1); gather(2, S2); });
    __syncthreads();                                  // children landed
    run_pass(S1, winlane, 12288, 256, winlane, 12288, 512, true, bb, acc, l15, q, noop);
    run_pass(S2, winlane, 12288, 512, w1lane, 4096, 0, true, bb, acc, l15, q, noop);
    __syncthreads();                                  // S1 reads done (all waves)
    store_elu(S1);
    __syncthreads();

    init_acc(bvb);
    run_pass(S1, w1lane, 4096, 0, w2lane, 4096, 0, true, bb, acc, l15, q, noop);
    __syncthreads();
    store_elu(S1);
    __syncthreads();

    init_acc(bvc);
    run_pass(S1, w2lane, 4096, 0, (const unsigned short*)nullptr, 0, 0, false,
             bb, acc, l15, q, noop);

    // ep3: o = root(S0) + H3 (+b2 in acc); in-place into S1 (lane-private)
#pragma unroll
    for (int mt = 0; mt < 2; ++mt)
#pragma unroll
        for (int nt = 0; nt < 4; ++nt)
#pragma unroll
            for (int rr = 0; rr < 4; ++rr) {
                int row = mt * 16 + q * 4 + rr;
                int col = n0 + nt * 16 + l15;
                int slot = (col >> 3) ^ (row & 7);
                float o = acc[mt][nt][rr] +
                          bf16_to_f32(S0[row * 256 + slot * 8 + (col & 7)]);
                S1[row * 256 + slot * 8 + (col & 7)] = f32_to_bf16(o);
            }
    __syncthreads();
#pragma unroll
    for (int it = 0; it < 4; ++it) {
        int r = it * 8 + sub;
        int c = s ^ (r & 7);
        *(short8*)(cur_out + (size_t)(blk * RR + r) * 256 + c * 8) =
            *(const short8*)(S1 + r * 256 + s * 8);
    }
}

// ---------------------------------------------------------------------------
// tree_tail: levels 32..1, one block per batch (64 blocks). Children of L=32
// from global (L=64 out); L<=16 staged LDS<-P. Same register B pipeline,
// chained across the 6 level-jobs.
// ---------------------------------------------------------------------------
__global__ __launch_bounds__(256, 2)
void tree_tail(const int* __restrict__ tokens,
               const unsigned short* __restrict__ Ebf,
               const unsigned short* __restrict__ Win,
               const unsigned short* __restrict__ W1,
               const unsigned short* __restrict__ W2,
               const float* __restrict__ b_in,
               const float* __restrict__ b1,
               const float* __restrict__ b2,
               const unsigned short* __restrict__ cur_in,   // L=64 out: 64 rows/batch
               float* __restrict__ out)
{
    __shared__ unsigned short S0[RR * 256];
    __shared__ unsigned short S1[RR * 256];
    __shared__ unsigned short S2[RR * 256];
    __shared__ unsigned short P[RR * 256];    // previous level output (<=32 rows)

    const int b    = blockIdx.x;
    const int tid  = threadIdx.x;
    const int lane = tid & 63;
    const int wid  = tid >> 6;
    const int l15  = lane & 15;
    const int q    = lane >> 4;
    const int n0   = wid * 64;
    const int s    = tid & 31;
    const int sub  = tid >> 5;

    float bva[4], bvb[4], bvc[4];
#pragma unroll
    for (int nt = 0; nt < 4; ++nt) {
        bva[nt] = b_in[n0 + nt * 16 + l15];
        bvb[nt] = b1[n0 + nt * 16 + l15];
        bvc[nt] = b2[n0 + nt * 16 + l15];
    }
    const unsigned short* winlane = Win + q * 8 + (size_t)(n0 + l15) * 768;
    const unsigned short* w1lane  = W1  + q * 8 + (size_t)(n0 + l15) * 256;
    const unsigned short* w2lane  = W2  + q * 8 + (size_t)(n0 + l15) * 256;

    f32x4 acc[2][4];
    auto init_acc = [&](const float* bv) {
#pragma unroll
        for (int mt = 0; mt < 2; ++mt)
#pragma unroll
            for (int nt = 0; nt < 4; ++nt)
                acc[mt][nt] = (f32x4){bv[nt], bv[nt], bv[nt], bv[nt]};
    };
    auto store_elu = [&](unsigned short* dst) {
#pragma unroll
        for (int mt = 0; mt < 2; ++mt)
#pragma unroll
            for (int nt = 0; nt < 4; ++nt)
#pragma unroll
                for (int rr = 0; rr < 4; ++rr) {
                    int row = mt * 16 + q * 4 + rr;
                    int col = n0 + nt * 16 + l15;
                    float h = acc[mt][nt][rr];
                    h = h > 0.f ? h : (__expf(h) - 1.f);
                    int slot = (col >> 3) ^ (row & 7);
                    dst[row * 256 + slot * 8 + (col & 7)] = f32_to_bf16(h);
                }
    };

    short8 bb[4][4];
    auto noop = []() {};

    // gather root of level L (rows clamped) into S0
    auto groot = [&](int L) {
#pragma unroll
        for (int it = 0; it < 4; ++it) {
            const int base_r = wid * 8 + it * 2;
            const int r = base_r + (lane >> 5);
            const int i = (r < L) ? r : 0;
            int tok = tokens[b * TOK_N + (L - 1) + i];
            const unsigned short* src = Ebf + (size_t)tok * 256;
            const int c = (lane & 31) ^ (r & 7);
            __builtin_amdgcn_global_load_lds(
                (gas_ptr)(const void*)(src + c * 8),
                (las_ptr)(void*)(S0 + base_r * 256), 16, 0, 0);
        }
    };
    // L==32 children from global cur_in
    auto gchild_g = [&](int p, unsigned short* dst) {
#pragma unroll
        for (int it = 0; it < 4; ++it) {
            const int base_r = wid * 8 + it * 2;
            const int r = base_r + (lane >> 5);
            const unsigned short* src = cur_in + ((size_t)b * 64 + 2 * r + (p - 1)) * 256;
            const int c = (lane & 31) ^ (r & 7);
            __builtin_amdgcn_global_load_lds(
                (gas_ptr)(const void*)(src + c * 8),
                (las_ptr)(void*)(dst + base_r * 256), 16, 0, 0);
        }
    };
    // L<=16 children staged from P (LDS->LDS)
    auto gchild_p = [&](int L) {
#pragma unroll
        for (int it = 0; it < 4; ++it) {
            int r = it * 8 + sub;
            int i = (r < L) ? r : 0;
            int c = s ^ (r & 7);
            int sl = 2 * i, sr = 2 * i + 1;
            *(short8*)(S1 + r * 256 + s * 8) = *(const short8*)(P + sl * 256 + ((c ^ (sl & 7))) * 8);
            *(short8*)(S2 + r * 256 + s * 8) = *(const short8*)(P + sr * 256 + ((c ^ (sr & 7))) * 8);
        }
    };

    // first job's B preload
#pragma unroll
    for (int j = 0; j < 4; ++j)
#pragma unroll
        for (int nt = 0; nt < 4; ++nt)
            bb[j][nt] = *(const short8*)(winlane + nt * 12288 + j * 32);

    for (int L = 32; L >= 1; L >>= 1) {
        const bool lastJob = (L == 1);
        groot(L);
        if (L == 32) { gchild_g(1, S1); gchild_g(2, S2); }
        else         gchild_p(L);
        __syncthreads();

        init_acc(bva);
        run_pass(S0, winlane, 12288, 0, winlane, 12288, 256, true, bb, acc, l15, q, noop);
        run_pass(S1, winlane, 12288, 256, winlane, 12288, 512, true, bb, acc, l15, q, noop);
        run_pass(S2, winlane, 12288, 512, w1lane, 4096, 0, true, bb, acc, l15, q, noop);
        __syncthreads();
        store_elu(S1);
        __syncthreads();

        init_acc(bvb);
        run_pass(S1, w1lane, 4096, 0, w2lane, 4096, 0, true, bb, acc, l15, q, noop);
        __syncthreads();
        store_elu(S1);
        __syncthreads();

        init_acc(bvc);
        run_pass(S1, w2lane, 4096, 0, winlane, 12288, 0, !lastJob, bb, acc, l15, q, noop);

        if (lastJob) {
#pragma unroll
            for (int mt = 0; mt < 2; ++mt)
#pragma unroll
                for (int nt = 0; nt < 4; ++nt)
#pragma unroll
                    for (int rr = 0; rr < 4; ++rr) {
                        int row = mt * 16 + q * 4 + rr;
                        if (row != 0) continue;
                        int col = n0 + nt * 16 + l15;
                        int slot = (col >> 3) ^ (row & 7);
                        float o = acc[mt][nt][rr] +
                                  bf16_to_f32(S0[row * 256 + slot * 8 + (col & 7)]);
                        out[(size_t)b * 256 + col] = o;
                    }
        } else {
#pragma unroll
            for (int mt = 0; mt < 2; ++mt)
#pragma unroll
                for (int nt = 0; nt < 4; ++nt)
#pragma unroll
                    for (int rr = 0; rr < 4; ++rr) {
                        int row = mt * 16 + q * 4 + rr;
                        int col = n0 + nt * 16 + l15;
                        int slot = (col >> 3) ^ (row & 7);
                        float o = acc[mt][nt][rr] +
                                  bf16_to_f32(S0[row * 256 + slot * 8 + (col & 7)]);
                        S1[row * 256 + slot * 8 + (col & 7)] = f32_to_bf16(o);
                    }
            __syncthreads();
            // S1 -> P (rows < L), same swizzle key (row&7)
#pragma unroll
            for (int it = 0; it < 4; ++it) {
                int r = it * 8 + sub;
                if (r < L)
                    *(short8*)(P + r * 256 + s * 8) = *(const short8*)(S1 + r * 256 + s * 8);
            }
            __syncthreads();
        }
    }
}

extern "C" void kernel_launch(void* const* d_in, const int* in_sizes, int n_in,
                              void* d_out, int out_size, void* d_ws, size_t ws_size,
                              hipStream_t stream) {
    const int*   tokens = (const int*)  d_in[0];
    const float* E      = (const float*)d_in[1];
    const float* W_in   = (const float*)d_in[2];
    const float* b_in   = (const float*)d_in[3];
    const float* W1     = (const float*)d_in[4];
    const float* b1     = (const float*)d_in[5];
    const float* W2     = (const float*)d_in[6];
    const float* b2     = (const float*)d_in[7];
    float* out = (float*)d_out;
    char* ws = (char*)d_ws;

    unsigned short* Ebf   = (unsigned short*)(ws);
    unsigned short* Winbf = (unsigned short*)(ws + 16416768);
    unsigned short* W1bf  = (unsigned short*)(ws + 16809984);
    unsigned short* W2bf  = (unsigned short*)(ws + 16941056);
    unsigned short* curA  = (unsigned short*)(ws + 17072128);
    unsigned short* curB  = (unsigned short*)(ws + 50626560);

    convert_f32_bf16<<<1024, 256, 0, stream>>>(E, W_in, W1, W2,
                                               Ebf, Winbf, W1bf, W2bf);

    const unsigned short* cin = curB;   // unused at first level
    unsigned short* cout = curA;
    int first = 1;
    for (int L = 1024; L >= 64; L >>= 1) {
        int logL = 31 - __builtin_clz((unsigned)L);
        tree_level<<<dim3(2 * L), dim3(256), 0, stream>>>(
            tokens, Ebf, Winbf, W1bf, W2bf, b_in, b1, b2, cin, cout, L, logL, first);
        cin = cout;
        cout = (cout == curA) ? curB : curA;
        first = 0;
    }
    // cin = L=64 output
    tree_tail<<<dim3(64), dim3(256), 0, stream>>>(
        tokens, Ebf, Winbf, W1bf, W2bf, b_in, b1, b2, cin, out);
}